// Round 1
// baseline (125.840 us; speedup 1.0000x reference)
//
#include <hip/hip_runtime.h>

// ContrastiveLoss on MI355X (gfx950)
// B=8192 rows, D=128, labels in [0,2048). loss = -(1/cnt) sum_i [ S_i/P_i - M - log Z_i ]
// with fixed softmax shift M = 1/0.07 (valid: normalized embeddings -> sim <= 1/T).

#define BATCH 8192
#define DIMK  128
#define INV_T 14.285714285714286f   // 1/0.07
#define MSUB  14.285714285714286f   // fixed softmax max-shift

typedef short bf16x8 __attribute__((ext_vector_type(8)));   // 8 bf16 = 4 VGPRs
typedef float f32x4  __attribute__((ext_vector_type(4)));

__device__ __forceinline__ unsigned short f2bf_rne(float f) {
    unsigned u = __float_as_uint(f);
    u += 0x7FFFu + ((u >> 16) & 1u);
    return (unsigned short)(u >> 16);
}

// fp32 -> bf16 conversion, 4 elems/thread. 1048576 elems = 1024 blocks * 256 thr * 4.
__global__ void cvt_bf16_kernel(const float* __restrict__ in, ushort* __restrict__ out) {
    int i = blockIdx.x * blockDim.x + threadIdx.x;
    float4 v = ((const float4*)in)[i];
    ushort4 o;
    o.x = f2bf_rne(v.x);
    o.y = f2bf_rne(v.y);
    o.z = f2bf_rne(v.z);
    o.w = f2bf_rne(v.w);
    ((ushort4*)out)[i] = o;
}

// Main fused kernel.
// Grid: (32, 16). Block: 256 (4 waves).
// Block covers rows [bx*256, bx*256+256) x cols [by*512, by*512+512).
// Wave w owns rows [bx*256 + w*64, +64) (4 m-tiles), iterates 32 n-tiles of 16 cols.
// MFMA 16x16x32_bf16: A-frag lane map A[m=lane&15][k=(lane>>4)*8+j];
// B-frag B[k=(lane>>4)*8+j][n=lane&15]; C/D: col=lane&15, row=(lane>>4)*4+reg.
// For A*A^T both frags load as E[tilebase+(lane&15)][kk*32+(lane>>4)*8 ..+8].
__global__ __launch_bounds__(256) void
contrastive_main(const ushort* __restrict__ Ebf, const int* __restrict__ labels,
                 float* __restrict__ zsum, float* __restrict__ ssum,
                 int* __restrict__ pcnt) {
    const int lane = threadIdx.x & 63;
    const int wid  = threadIdx.x >> 6;
    const int quad = lane >> 4;
    const int l16  = lane & 15;
    const int row_base = blockIdx.x * 256 + wid * 64;
    const int col_base = blockIdx.y * 512;

    // Preload A fragments for this wave's 64 rows (register-resident).
    bf16x8 afrag[4][4];
#pragma unroll
    for (int mt = 0; mt < 4; ++mt) {
#pragma unroll
        for (int kk = 0; kk < 4; ++kk) {
            const ushort* p = Ebf + (size_t)(row_base + mt * 16 + l16) * DIMK
                              + kk * 32 + quad * 8;
            afrag[mt][kk] = *(const bf16x8*)p;
        }
    }

    // Row labels for this lane's 16 row-slots (slot s -> row mt*16 + quad*4 + r).
    int labr[16];
#pragma unroll
    for (int s = 0; s < 16; ++s) {
        int row = row_base + (s >> 2) * 16 + quad * 4 + (s & 3);
        labr[s] = labels[row];
    }

    float zacc[16], sacc[16];
    int pacc[16];
#pragma unroll
    for (int s = 0; s < 16; ++s) { zacc[s] = 0.f; sacc[s] = 0.f; pacc[s] = 0; }

    for (int nt = 0; nt < 32; ++nt) {
        const int colb = col_base + nt * 16;
        bf16x8 bfrag[4];
#pragma unroll
        for (int kk = 0; kk < 4; ++kk) {
            const ushort* p = Ebf + (size_t)(colb + l16) * DIMK + kk * 32 + quad * 8;
            bfrag[kk] = *(const bf16x8*)p;
        }
        const int labc = labels[colb + l16];
        const int col  = colb + l16;

#pragma unroll
        for (int mt = 0; mt < 4; ++mt) {
            f32x4 c = {0.f, 0.f, 0.f, 0.f};
#pragma unroll
            for (int kk = 0; kk < 4; ++kk)
                c = __builtin_amdgcn_mfma_f32_16x16x32_bf16(afrag[mt][kk], bfrag[kk], c, 0, 0, 0);
#pragma unroll
            for (int r = 0; r < 4; ++r) {
                const int slot = mt * 4 + r;
                const int row  = row_base + mt * 16 + quad * 4 + r;
                const float sim = c[r] * INV_T;
                const float e = __expf(sim - MSUB);
                const bool ok = (row != col);
                zacc[slot] += ok ? e : 0.0f;
                const bool pos = ok && (labr[slot] == labc);
                sacc[slot] += pos ? sim : 0.0f;
                pacc[slot] += pos ? 1 : 0;
            }
        }
    }

    // Reduce each row-slot across the 16 lanes sharing the row (xor over low 4 bits),
    // then one atomic per row per block.
#pragma unroll
    for (int s = 0; s < 16; ++s) {
        float z = zacc[s], sv = sacc[s];
        int pv = pacc[s];
#pragma unroll
        for (int m = 1; m <= 8; m <<= 1) {
            z  += __shfl_xor(z, m, 64);
            sv += __shfl_xor(sv, m, 64);
            pv += __shfl_xor(pv, m, 64);
        }
        if (l16 == 0) {
            int row = row_base + (s >> 2) * 16 + quad * 4 + (s & 3);
            atomicAdd(&zsum[row], z);
            atomicAdd(&ssum[row], sv);
            atomicAdd(&pcnt[row], pv);
        }
    }
}

// Final reduction over 8192 rows -> scalar loss.
__global__ void finalize_kernel(const float* __restrict__ zsum,
                                const float* __restrict__ ssum,
                                const int* __restrict__ pcnt,
                                float* __restrict__ out) {
    __shared__ float wsum[4];
    __shared__ int wcnt[4];
    float local = 0.f;
    int lc = 0;
    for (int r = threadIdx.x; r < BATCH; r += 256) {
        int p = pcnt[r];
        if (p > 0) {
            local += ssum[r] / (float)p - MSUB - logf(zsum[r]);
            lc++;
        }
    }
#pragma unroll
    for (int m = 1; m < 64; m <<= 1) {
        local += __shfl_xor(local, m, 64);
        lc    += __shfl_xor(lc, m, 64);
    }
    int wid = threadIdx.x >> 6;
    if ((threadIdx.x & 63) == 0) { wsum[wid] = local; wcnt[wid] = lc; }
    __syncthreads();
    if (threadIdx.x == 0) {
        float t = 0.f;
        int c = 0;
        for (int w = 0; w < 4; ++w) { t += wsum[w]; c += wcnt[w]; }
        out[0] = -t / (float)(c > 0 ? c : 1);
    }
}

extern "C" void kernel_launch(void* const* d_in, const int* in_sizes, int n_in,
                              void* d_out, int out_size, void* d_ws, size_t ws_size,
                              hipStream_t stream) {
    const float* emb   = (const float*)d_in[0];
    const int* labels  = (const int*)d_in[1];
    float* out         = (float*)d_out;

    char* ws = (char*)d_ws;
    ushort* Ebf = (ushort*)ws;                                   // 8192*128*2 = 2 MB
    float* zsum = (float*)(ws + 2 * 1024 * 1024);                // 32 KB
    float* ssum = (float*)(ws + 2 * 1024 * 1024 + 32768);        // 32 KB
    int*   pcnt = (int*)  (ws + 2 * 1024 * 1024 + 65536);        // 32 KB

    hipMemsetAsync(ws + 2 * 1024 * 1024, 0, 3 * 32768, stream);
    cvt_bf16_kernel<<<1024, 256, 0, stream>>>(emb, Ebf);
    dim3 grid(32, 16);
    contrastive_main<<<grid, 256, 0, stream>>>(Ebf, labels, zsum, ssum, pcnt);
    finalize_kernel<<<1, 256, 0, stream>>>(zsum, ssum, pcnt, out);
}